// Round 16
// baseline (314.194 us; speedup 1.0000x reference)
//
#include <hip/hip_runtime.h>

// Mamba-2 SSD chunked scan — fused persistent kernel (round 16).
// Skeleton = r13 (1 barrier/chunk, 131.5us). r14 failed: rbuf[ci] runtime idx
// -> scratch. r15 failed: lambda ARRAY-REFERENCE params -> address-taken ->
// scratch (WRITE 267MB). Round-16: same pinned-prefetch idea via PREPROCESSOR
// MACRO — body duplicated with literal names rbA/rbB, zero refs, zero runtime
// private indices. Canaries: WRITE_SIZE==131072 KB exactly + FETCH ~337MB
// (scratch gone), VGPR 100-140 (prefetch regs live across phase), absmax<=1.

typedef __bf16 bf16x4 __attribute__((ext_vector_type(4)));
typedef __bf16 bf16x8 __attribute__((ext_vector_type(8)));
typedef float  f32x4  __attribute__((ext_vector_type(4)));

constexpr int LDT = 72;   // bf16 row stride (144 B)

__device__ __forceinline__ f32x4 mfma16(bf16x8 a, bf16x8 b, f32x4 c) {
    return __builtin_amdgcn_mfma_f32_16x16x32_bf16(a, b, c, 0, 0, 0);
}
__device__ __forceinline__ void bar_lds() {
    asm volatile("s_waitcnt lgkmcnt(0)\n\ts_barrier" ::: "memory");
}
__device__ __forceinline__ int swz(int row, int byteoff) {
    return byteoff ^ (((row >> 2) & 7) << 4);
}

struct SMemF {
    __bf16 Cm[2][64][LDT];
    __bf16 Bm[2][64][LDT];
    __bf16 Bt[2][64][LDT];   // swizzled
    __bf16 Mm[2][64][LDT];
    __bf16 Xt[3][32][LDT];   // swizzled, triple
    __bf16 St16[2][32][LDT];
    float  St32[32][68];
    float  sY[2][64][36];
    float  ds[4][64];
    float  dout[4][64];
    float  douti[4][64];
    float  dlast[4];
};

// One chunk phase. CC=runtime chunk idx, CI=literal 0/1 parity,
// RBW/RXW = prefetch dest regs (chunk CC+2), RBR/RXR = stage source (CC+1).
#define PHASE(CC, CI, RBW, RXW, RBR, RXR)                                          \
    {                                                                              \
        const int c  = (CC);                                                       \
        const int nb = (CI) ^ 1;                                                   \
        const int t0 = c & 3, t1 = (c+1) & 3, t2 = (c+2) & 3, t3 = (c+3) & 3;      \
        if (c < 62) {                                                              \
            const size_t s2 = tbase + (size_t)(c + 2)*64;                          \
            _Pragma("unroll")                                                      \
            for (int j = 0; j < 4; ++j) {                                          \
                const int row = (half == 0) ? (lt0 + j) : (rr0 + 16*j);            \
                const size_t go = ((s2 + row)*16 + hh)*(size_t)64 + cq0;           \
                *reinterpret_cast<float4*>(RBW[j]) = (half == 0)                   \
                    ? *reinterpret_cast<const float4*>(&Bg[go])                    \
                    : *reinterpret_cast<const float4*>(&Cg[go]);                   \
            }                                                                      \
            *reinterpret_cast<float4*>(RXW) = *reinterpret_cast<const float4*>(    \
                &Xg[((s2 + xl)*16 + hh)*(size_t)64 + ph*32 + xp4]);                \
        }                                                                          \
        __builtin_amdgcn_sched_barrier(0);                                         \
        f32x4 g0 = {}, g1 = {}, aoacc = {}, stacc = {};                            \
        _Pragma("unroll")                                                          \
        for (int ks = 0; ks < 2; ++ks) {                                           \
            const int k0 = ks*32 + fg*8;                                           \
            const bf16x8 aC  = *reinterpret_cast<const bf16x8*>(&sm.Cm[CI][iw2 + fr][k0]);      \
            const bf16x8 bB0 = *reinterpret_cast<const bf16x8*>(&sm.Bm[CI][jh      + fr][k0]);  \
            const bf16x8 bB1 = *reinterpret_cast<const bf16x8*>(&sm.Bm[CI][jh + 16 + fr][k0]);  \
            const bf16x8 bSt = *reinterpret_cast<const bf16x8*>(&sm.St16[CI][pt + fr][k0]);     \
            const bf16x8 aBt = *reinterpret_cast<const bf16x8*>(                   \
                reinterpret_cast<const char*>(&sm.Bt[CI][iw2 + fr][0]) + swz(iw2 + fr, k0*2));  \
            const bf16x8 bXt = *reinterpret_cast<const bf16x8*>(                   \
                reinterpret_cast<const char*>(&sm.Xt[x0][pt + fr][0]) + swz(pt + fr, k0*2));    \
            g0    = mfma16(aC,  bB0, g0);                                          \
            g1    = mfma16(aC,  bB1, g1);                                          \
            aoacc = mfma16(aC,  bSt, aoacc);                                       \
            stacc = mfma16(aBt, bXt, stacc);                                       \
        }                                                                          \
        f32x4 ad = {};                                                             \
        if (c > 0) {                                                               \
            _Pragma("unroll")                                                      \
            for (int ks = 0; ks < 2; ++ks) {                                       \
                const int k0 = ks*32 + fg*8;                                       \
                const bf16x8 aM = *reinterpret_cast<const bf16x8*>(&sm.Mm[nb][iw2 + fr][k0]);   \
                const bf16x8 bX = *reinterpret_cast<const bf16x8*>(                \
                    reinterpret_cast<const char*>(&sm.Xt[x2][pt + fr][0]) + swz(pt + fr, k0*2));\
                ad = mfma16(aM, bX, ad);                                           \
            }                                                                      \
        }                                                                          \
        if (c <= 61 && wid == 0) {                                                 \
            float v = aA;                                                          \
            _Pragma("unroll")                                                      \
            for (int o = 1; o < 64; o <<= 1) { float t = __shfl_up(v, o, 64); if (lane >= o) v += t; } \
            const float last = __shfl(v, 63, 64);                                  \
            sm.ds[t2][lane]    = expf(last - v);                                   \
            sm.dout[t2][lane]  = expf(v);                                          \
            sm.douti[t2][lane] = expf(v - last);                                   \
            if (lane == 63) sm.dlast[t2] = expf(v);                                \
        }                                                                          \
        if (c >= 2) {                                                              \
            const float4 v = *reinterpret_cast<const float4*>(&sm.sY[nb][xl][xp4]);\
            *reinterpret_cast<float4*>(                                            \
                &Yg[((tbase + (size_t)(c-2)*64 + xl)*16 + hh)*(size_t)64 + ph*32 + xp4]) = v;   \
        }                                                                          \
        if (c < 63) {                                                              \
            if (half == 0) {                                                       \
                _Pragma("unroll")                                                  \
                for (int j = 0; j < 4; ++j)                                        \
                    *reinterpret_cast<bf16x4*>(&sm.Bm[nb][lt0 + j][cq0]) =         \
                        (bf16x4){(__bf16)RBR[j][0], (__bf16)RBR[j][1],             \
                                 (__bf16)RBR[j][2], (__bf16)RBR[j][3]};            \
                _Pragma("unroll")                                                  \
                for (int q = 0; q < 4; ++q)                                        \
                    *reinterpret_cast<bf16x4*>(                                    \
                        reinterpret_cast<char*>(&sm.Bt[nb][cq0 + q][0]) + swz(cq0 + q, lt0*2)) =\
                        (bf16x4){(__bf16)RBR[0][q], (__bf16)RBR[1][q],             \
                                 (__bf16)RBR[2][q], (__bf16)RBR[3][q]};            \
            } else {                                                               \
                _Pragma("unroll")                                                  \
                for (int j = 0; j < 4; ++j)                                        \
                    *reinterpret_cast<bf16x4*>(&sm.Cm[nb][rr0 + 16*j][cq0]) =      \
                        (bf16x4){(__bf16)RBR[j][0], (__bf16)RBR[j][1],             \
                                 (__bf16)RBR[j][2], (__bf16)RBR[j][3]};            \
            }                                                                      \
            const float dsl = sm.ds[t1][xl];                                       \
            _Pragma("unroll")                                                      \
            for (int q = 0; q < 4; ++q)                                            \
                *reinterpret_cast<__bf16*>(                                        \
                    reinterpret_cast<char*>(&sm.Xt[x1][xp4 + q][0]) + swz(xp4 + q, xl*2)) =     \
                    (__bf16)(RXR[q] * dsl);                                        \
        }                                                                          \
        if (wid == 0 && c <= 60) aA = Ag[(tbase + (size_t)(c + 3)*64 + lane)*16 + hh];          \
        if (c > 0) {                                                               \
            _Pragma("unroll")                                                      \
            for (int r = 0; r < 4; ++r) {                                          \
                const int i = iw2 + fg*4 + r;                                      \
                sm.sY[CI][i][pt + fr] = ad[r] + sm.dout[t3][i] * aoprev[r];        \
            }                                                                      \
        }                                                                          \
        _Pragma("unroll")                                                          \
        for (int jt = 0; jt < 2; ++jt) {                                           \
            const int j = jh + jt*16 + fr;                                         \
            const f32x4& gg = jt ? g1 : g0;                                        \
            _Pragma("unroll")                                                      \
            for (int r = 0; r < 4; ++r) {                                          \
                const int i = iw2 + fg*4 + r;                                      \
                const float val = (i >= j) ? gg[r] * sm.douti[t0][i] : 0.0f;       \
                sm.Mm[CI][i][j] = (__bf16)val;                                     \
            }                                                                      \
        }                                                                          \
        if (c < 63) {                                                              \
            const float dl = sm.dlast[t0];                                         \
            const int p = pt + fr, n0 = iw2 + fg*4;                                \
            const float4 ov = *reinterpret_cast<const float4*>(&sm.St32[p][n0]);   \
            float4 nv;                                                             \
            nv.x = fmaf(dl, ov.x, stacc[0]); nv.y = fmaf(dl, ov.y, stacc[1]);      \
            nv.z = fmaf(dl, ov.z, stacc[2]); nv.w = fmaf(dl, ov.w, stacc[3]);      \
            *reinterpret_cast<float4*>(&sm.St32[p][n0]) = nv;                      \
            *reinterpret_cast<bf16x4*>(&sm.St16[nb][p][n0]) =                      \
                (bf16x4){(__bf16)nv.x, (__bf16)nv.y, (__bf16)nv.z, (__bf16)nv.w};  \
        }                                                                          \
        aoprev = aoacc;                                                            \
        bar_lds();                                                                 \
        const int xt = x0; x0 = x1; x1 = x2; x2 = xt;                              \
    }

__global__ void ssd_fused(const float* __restrict__ Xg, const float* __restrict__ Ig,
                          const float* __restrict__ Ag, const float* __restrict__ Bg,
                          const float* __restrict__ Cg, float* __restrict__ Yg)
{
    const int ph = blockIdx.x, hh = blockIdx.y, bb = blockIdx.z;
    const int tid = threadIdx.x;            // 0..511
    const int wid = tid >> 6, lane = tid & 63;
    const int fr = lane & 15, fg = lane >> 4;
    const int iw2 = (wid >> 1) * 16;
    const int pt  = (wid & 1) * 16;
    const int jh  = (wid & 1) * 32;

    __shared__ __align__(16) SMemF sm;
    const size_t tbase = (size_t)bb * 4096;

    const int half = tid >> 8;
    const int u    = tid & 255;
    const int lt0  = (u >> 4) * 4;
    const int rr0  = u >> 4;
    const int cq0  = (u & 15) * 4;
    const int xl  = tid >> 3;
    const int xp4 = (tid & 7) * 4;
    const int sp  = tid >> 4;
    const int sn4 = (tid & 15) * 4;

    float rbA[4][4], rxA[4], rbB[4][4], rxB[4];   // named, never referenced
    float aA = 0.0f;
    f32x4 aoprev = {};
    int x0 = 0, x1 = 1, x2 = 2;

    // ---------------- prologue ----------------
    {
        const size_t iofs = (((size_t)bb*16 + hh)*64 + (ph*32 + sp))*(size_t)64 + sn4;
        const float4 v = *reinterpret_cast<const float4*>(&Ig[iofs]);
        sm.St32[sp][sn4+0] = v.x; sm.St32[sp][sn4+1] = v.y;
        sm.St32[sp][sn4+2] = v.z; sm.St32[sp][sn4+3] = v.w;
        *reinterpret_cast<bf16x4*>(&sm.St16[0][sp][sn4]) =
            (bf16x4){(__bf16)v.x, (__bf16)v.y, (__bf16)v.z, (__bf16)v.w};
    }
    #pragma unroll
    for (int j = 0; j < 4; ++j) {
        const int row = (half == 0) ? (lt0 + j) : (rr0 + 16*j);
        const size_t go = ((tbase + row)*16 + hh)*(size_t)64 + cq0;
        *reinterpret_cast<float4*>(rbA[j]) = (half == 0)
            ? *reinterpret_cast<const float4*>(&Bg[go])
            : *reinterpret_cast<const float4*>(&Cg[go]);
    }
    *reinterpret_cast<float4*>(rxA) =
        *reinterpret_cast<const float4*>(&Xg[((tbase + xl)*16 + hh)*(size_t)64 + ph*32 + xp4]);
    if (wid < 2) {   // scans for chunks 0,1
        float v = Ag[(tbase + wid*64 + lane)*16 + hh];
        #pragma unroll
        for (int o = 1; o < 64; o <<= 1) { float t = __shfl_up(v, o, 64); if (lane >= o) v += t; }
        const float last = __shfl(v, 63, 64);
        sm.ds[wid][lane]    = expf(last - v);
        sm.dout[wid][lane]  = expf(v);
        sm.douti[wid][lane] = expf(v - last);
        if (lane == 63) sm.dlast[wid] = expf(v);
    }
    if (half == 0) {
        #pragma unroll
        for (int j = 0; j < 4; ++j)
            *reinterpret_cast<bf16x4*>(&sm.Bm[0][lt0 + j][cq0]) =
                (bf16x4){(__bf16)rbA[j][0], (__bf16)rbA[j][1], (__bf16)rbA[j][2], (__bf16)rbA[j][3]};
        #pragma unroll
        for (int q = 0; q < 4; ++q)
            *reinterpret_cast<bf16x4*>(
                reinterpret_cast<char*>(&sm.Bt[0][cq0 + q][0]) + swz(cq0 + q, lt0*2)) =
                (bf16x4){(__bf16)rbA[0][q], (__bf16)rbA[1][q], (__bf16)rbA[2][q], (__bf16)rbA[3][q]};
    } else {
        #pragma unroll
        for (int j = 0; j < 4; ++j)
            *reinterpret_cast<bf16x4*>(&sm.Cm[0][rr0 + 16*j][cq0]) =
                (bf16x4){(__bf16)rbA[j][0], (__bf16)rbA[j][1], (__bf16)rbA[j][2], (__bf16)rbA[j][3]};
    }
    bar_lds();
    {
        const float dsl = sm.ds[0][xl];
        #pragma unroll
        for (int q = 0; q < 4; ++q)
            *reinterpret_cast<__bf16*>(
                reinterpret_cast<char*>(&sm.Xt[0][xp4 + q][0]) + swz(xp4 + q, xl*2)) =
                (__bf16)(rxA[q] * dsl);
    }
    #pragma unroll
    for (int j = 0; j < 4; ++j) {   // chunk-1 loads -> rbB
        const int row = (half == 0) ? (lt0 + j) : (rr0 + 16*j);
        const size_t go = ((tbase + 64 + row)*16 + hh)*(size_t)64 + cq0;
        *reinterpret_cast<float4*>(rbB[j]) = (half == 0)
            ? *reinterpret_cast<const float4*>(&Bg[go])
            : *reinterpret_cast<const float4*>(&Cg[go]);
    }
    *reinterpret_cast<float4*>(rxB) =
        *reinterpret_cast<const float4*>(&Xg[((tbase + 64 + xl)*16 + hh)*(size_t)64 + ph*32 + xp4]);
    if (wid == 0) aA = Ag[(tbase + 2*64 + lane)*16 + hh];
    bar_lds();

    // ---------------- chunk loop: unrolled x2, macro-expanded ----------------
    for (int cb = 0; cb < 64; cb += 2) {
        PHASE(cb,     0, rbA, rxA, rbB, rxB)   // even: prefetch->A, stage<-B
        PHASE(cb + 1, 1, rbB, rxB, rbA, rxA)   // odd:  prefetch->B, stage<-A
    }

    // ---------------- epilogue: ad(63), Y(62), Y(63) ----------------
    {
        f32x4 ad = {};
        #pragma unroll
        for (int ks = 0; ks < 2; ++ks) {
            const int k0 = ks*32 + fg*8;
            const bf16x8 aM = *reinterpret_cast<const bf16x8*>(&sm.Mm[1][iw2 + fr][k0]);
            const bf16x8 bX = *reinterpret_cast<const bf16x8*>(
                reinterpret_cast<const char*>(&sm.Xt[x2][pt + fr][0]) + swz(pt + fr, k0*2));
            ad = mfma16(aM, bX, ad);
        }
        #pragma unroll
        for (int r = 0; r < 4; ++r) {
            const int i = iw2 + fg*4 + r;
            sm.sY[0][i][pt + fr] = ad[r] + sm.dout[3][i] * aoprev[r];
        }
    }
    {
        const float4 v = *reinterpret_cast<const float4*>(&sm.sY[1][xl][xp4]);
        *reinterpret_cast<float4*>(
            &Yg[((tbase + (size_t)62*64 + xl)*16 + hh)*(size_t)64 + ph*32 + xp4]) = v;
    }
    bar_lds();
    {
        const float4 v = *reinterpret_cast<const float4*>(&sm.sY[0][xl][xp4]);
        *reinterpret_cast<float4*>(
            &Yg[((tbase + (size_t)63*64 + xl)*16 + hh)*(size_t)64 + ph*32 + xp4]) = v;
    }
}

extern "C" void kernel_launch(void* const* d_in, const int* in_sizes, int n_in,
                              void* d_out, int out_size, void* d_ws, size_t ws_size,
                              hipStream_t stream) {
    const float* X  = (const float*)d_in[0];
    const float* I  = (const float*)d_in[1];
    const float* A  = (const float*)d_in[2];
    const float* Bp = (const float*)d_in[3];
    const float* Cp = (const float*)d_in[4];
    float* Y = (float*)d_out;
    ssd_fused<<<dim3(2, 16, 8), 512, 0, stream>>>(X, I, A, Bp, Cp, Y);
}

// Round 17
// 162.569 us; speedup vs baseline: 1.9327x; 1.9327x over previous
//
#include <hip/hip_runtime.h>

// Mamba-2 SSD chunked scan — fused persistent kernel (round 17).
// = r16 macro structure + ONE change: __launch_bounds__(512, 2).
// DIAGNOSIS of r14/r15/r16 triple-failure: VGPR pinned at 64 in all three.
// Without launch_bounds the compiler targets default occupancy (ignorant that
// 127KB LDS already limits us to 1 block/CU = 2 waves/SIMD) and meets that
// target by SPILLING (WRITE_SIZE 267-638MB) instead of allocating >64 VGPRs.
// __launch_bounds__(512, 2) declares the true occupancy -> VGPR budget 256 ->
// double-buffered prefetch regs stay resident, pin holds, full phase covers
// HBM latency. (Opposite of r7/r8's error: this RAISES the ceiling to match
// reality, not caps it below need.)
// Canaries: VGPR>=100 (pin worked), WRITE_SIZE==131072 KB exactly (no
// scratch), LDS==127488, absmax<=1.

typedef __bf16 bf16x4 __attribute__((ext_vector_type(4)));
typedef __bf16 bf16x8 __attribute__((ext_vector_type(8)));
typedef float  f32x4  __attribute__((ext_vector_type(4)));

constexpr int LDT = 72;   // bf16 row stride (144 B)

__device__ __forceinline__ f32x4 mfma16(bf16x8 a, bf16x8 b, f32x4 c) {
    return __builtin_amdgcn_mfma_f32_16x16x32_bf16(a, b, c, 0, 0, 0);
}
__device__ __forceinline__ void bar_lds() {
    asm volatile("s_waitcnt lgkmcnt(0)\n\ts_barrier" ::: "memory");
}
__device__ __forceinline__ int swz(int row, int byteoff) {
    return byteoff ^ (((row >> 2) & 7) << 4);
}

struct SMemF {
    __bf16 Cm[2][64][LDT];
    __bf16 Bm[2][64][LDT];
    __bf16 Bt[2][64][LDT];   // swizzled
    __bf16 Mm[2][64][LDT];
    __bf16 Xt[3][32][LDT];   // swizzled, triple
    __bf16 St16[2][32][LDT];
    float  St32[32][68];
    float  sY[2][64][36];
    float  ds[4][64];
    float  dout[4][64];
    float  douti[4][64];
    float  dlast[4];
};

// One chunk phase. CC=runtime chunk idx, CI=literal 0/1 parity,
// RBW/RXW = prefetch dest regs (chunk CC+2), RBR/RXR = stage source (CC+1).
#define PHASE(CC, CI, RBW, RXW, RBR, RXR)                                          \
    {                                                                              \
        const int c  = (CC);                                                       \
        const int nb = (CI) ^ 1;                                                   \
        const int t0 = c & 3, t1 = (c+1) & 3, t2 = (c+2) & 3, t3 = (c+3) & 3;      \
        if (c < 62) {                                                              \
            const size_t s2 = tbase + (size_t)(c + 2)*64;                          \
            _Pragma("unroll")                                                      \
            for (int j = 0; j < 4; ++j) {                                          \
                const int row = (half == 0) ? (lt0 + j) : (rr0 + 16*j);            \
                const size_t go = ((s2 + row)*16 + hh)*(size_t)64 + cq0;           \
                *reinterpret_cast<float4*>(RBW[j]) = (half == 0)                   \
                    ? *reinterpret_cast<const float4*>(&Bg[go])                    \
                    : *reinterpret_cast<const float4*>(&Cg[go]);                   \
            }                                                                      \
            *reinterpret_cast<float4*>(RXW) = *reinterpret_cast<const float4*>(    \
                &Xg[((s2 + xl)*16 + hh)*(size_t)64 + ph*32 + xp4]);                \
        }                                                                          \
        __builtin_amdgcn_sched_barrier(0);                                         \
        f32x4 g0 = {}, g1 = {}, aoacc = {}, stacc = {};                            \
        _Pragma("unroll")                                                          \
        for (int ks = 0; ks < 2; ++ks) {                                           \
            const int k0 = ks*32 + fg*8;                                           \
            const bf16x8 aC  = *reinterpret_cast<const bf16x8*>(&sm.Cm[CI][iw2 + fr][k0]);      \
            const bf16x8 bB0 = *reinterpret_cast<const bf16x8*>(&sm.Bm[CI][jh      + fr][k0]);  \
            const bf16x8 bB1 = *reinterpret_cast<const bf16x8*>(&sm.Bm[CI][jh + 16 + fr][k0]);  \
            const bf16x8 bSt = *reinterpret_cast<const bf16x8*>(&sm.St16[CI][pt + fr][k0]);     \
            const bf16x8 aBt = *reinterpret_cast<const bf16x8*>(                   \
                reinterpret_cast<const char*>(&sm.Bt[CI][iw2 + fr][0]) + swz(iw2 + fr, k0*2));  \
            const bf16x8 bXt = *reinterpret_cast<const bf16x8*>(                   \
                reinterpret_cast<const char*>(&sm.Xt[x0][pt + fr][0]) + swz(pt + fr, k0*2));    \
            g0    = mfma16(aC,  bB0, g0);                                          \
            g1    = mfma16(aC,  bB1, g1);                                          \
            aoacc = mfma16(aC,  bSt, aoacc);                                       \
            stacc = mfma16(aBt, bXt, stacc);                                       \
        }                                                                          \
        f32x4 ad = {};                                                             \
        if (c > 0) {                                                               \
            _Pragma("unroll")                                                      \
            for (int ks = 0; ks < 2; ++ks) {                                       \
                const int k0 = ks*32 + fg*8;                                       \
                const bf16x8 aM = *reinterpret_cast<const bf16x8*>(&sm.Mm[nb][iw2 + fr][k0]);   \
                const bf16x8 bX = *reinterpret_cast<const bf16x8*>(                \
                    reinterpret_cast<const char*>(&sm.Xt[x2][pt + fr][0]) + swz(pt + fr, k0*2));\
                ad = mfma16(aM, bX, ad);                                           \
            }                                                                      \
        }                                                                          \
        if (c <= 61 && wid == 0) {                                                 \
            float v = aA;                                                          \
            _Pragma("unroll")                                                      \
            for (int o = 1; o < 64; o <<= 1) { float t = __shfl_up(v, o, 64); if (lane >= o) v += t; } \
            const float last = __shfl(v, 63, 64);                                  \
            sm.ds[t2][lane]    = expf(last - v);                                   \
            sm.dout[t2][lane]  = expf(v);                                          \
            sm.douti[t2][lane] = expf(v - last);                                   \
            if (lane == 63) sm.dlast[t2] = expf(v);                                \
        }                                                                          \
        if (c >= 2) {                                                              \
            const float4 v = *reinterpret_cast<const float4*>(&sm.sY[nb][xl][xp4]);\
            *reinterpret_cast<float4*>(                                            \
                &Yg[((tbase + (size_t)(c-2)*64 + xl)*16 + hh)*(size_t)64 + ph*32 + xp4]) = v;   \
        }                                                                          \
        if (c < 63) {                                                              \
            if (half == 0) {                                                       \
                _Pragma("unroll")                                                  \
                for (int j = 0; j < 4; ++j)                                        \
                    *reinterpret_cast<bf16x4*>(&sm.Bm[nb][lt0 + j][cq0]) =         \
                        (bf16x4){(__bf16)RBR[j][0], (__bf16)RBR[j][1],             \
                                 (__bf16)RBR[j][2], (__bf16)RBR[j][3]};            \
                _Pragma("unroll")                                                  \
                for (int q = 0; q < 4; ++q)                                        \
                    *reinterpret_cast<bf16x4*>(                                    \
                        reinterpret_cast<char*>(&sm.Bt[nb][cq0 + q][0]) + swz(cq0 + q, lt0*2)) =\
                        (bf16x4){(__bf16)RBR[0][q], (__bf16)RBR[1][q],             \
                                 (__bf16)RBR[2][q], (__bf16)RBR[3][q]};            \
            } else {                                                               \
                _Pragma("unroll")                                                  \
                for (int j = 0; j < 4; ++j)                                        \
                    *reinterpret_cast<bf16x4*>(&sm.Cm[nb][rr0 + 16*j][cq0]) =      \
                        (bf16x4){(__bf16)RBR[j][0], (__bf16)RBR[j][1],             \
                                 (__bf16)RBR[j][2], (__bf16)RBR[j][3]};            \
            }                                                                      \
            const float dsl = sm.ds[t1][xl];                                       \
            _Pragma("unroll")                                                      \
            for (int q = 0; q < 4; ++q)                                            \
                *reinterpret_cast<__bf16*>(                                        \
                    reinterpret_cast<char*>(&sm.Xt[x1][xp4 + q][0]) + swz(xp4 + q, xl*2)) =     \
                    (__bf16)(RXR[q] * dsl);                                        \
        }                                                                          \
        if (wid == 0 && c <= 60) aA = Ag[(tbase + (size_t)(c + 3)*64 + lane)*16 + hh];          \
        if (c > 0) {                                                               \
            _Pragma("unroll")                                                      \
            for (int r = 0; r < 4; ++r) {                                          \
                const int i = iw2 + fg*4 + r;                                      \
                sm.sY[CI][i][pt + fr] = ad[r] + sm.dout[t3][i] * aoprev[r];        \
            }                                                                      \
        }                                                                          \
        _Pragma("unroll")                                                          \
        for (int jt = 0; jt < 2; ++jt) {                                           \
            const int j = jh + jt*16 + fr;                                         \
            const f32x4& gg = jt ? g1 : g0;                                        \
            _Pragma("unroll")                                                      \
            for (int r = 0; r < 4; ++r) {                                          \
                const int i = iw2 + fg*4 + r;                                      \
                const float val = (i >= j) ? gg[r] * sm.douti[t0][i] : 0.0f;       \
                sm.Mm[CI][i][j] = (__bf16)val;                                     \
            }                                                                      \
        }                                                                          \
        if (c < 63) {                                                              \
            const float dl = sm.dlast[t0];                                         \
            const int p = pt + fr, n0 = iw2 + fg*4;                                \
            const float4 ov = *reinterpret_cast<const float4*>(&sm.St32[p][n0]);   \
            float4 nv;                                                             \
            nv.x = fmaf(dl, ov.x, stacc[0]); nv.y = fmaf(dl, ov.y, stacc[1]);      \
            nv.z = fmaf(dl, ov.z, stacc[2]); nv.w = fmaf(dl, ov.w, stacc[3]);      \
            *reinterpret_cast<float4*>(&sm.St32[p][n0]) = nv;                      \
            *reinterpret_cast<bf16x4*>(&sm.St16[nb][p][n0]) =                      \
                (bf16x4){(__bf16)nv.x, (__bf16)nv.y, (__bf16)nv.z, (__bf16)nv.w};  \
        }                                                                          \
        aoprev = aoacc;                                                            \
        bar_lds();                                                                 \
        const int xt = x0; x0 = x1; x1 = x2; x2 = xt;                              \
    }

__global__ __launch_bounds__(512, 2)
void ssd_fused(const float* __restrict__ Xg, const float* __restrict__ Ig,
               const float* __restrict__ Ag, const float* __restrict__ Bg,
               const float* __restrict__ Cg, float* __restrict__ Yg)
{
    const int ph = blockIdx.x, hh = blockIdx.y, bb = blockIdx.z;
    const int tid = threadIdx.x;            // 0..511
    const int wid = tid >> 6, lane = tid & 63;
    const int fr = lane & 15, fg = lane >> 4;
    const int iw2 = (wid >> 1) * 16;
    const int pt  = (wid & 1) * 16;
    const int jh  = (wid & 1) * 32;

    __shared__ __align__(16) SMemF sm;
    const size_t tbase = (size_t)bb * 4096;

    const int half = tid >> 8;
    const int u    = tid & 255;
    const int lt0  = (u >> 4) * 4;
    const int rr0  = u >> 4;
    const int cq0  = (u & 15) * 4;
    const int xl  = tid >> 3;
    const int xp4 = (tid & 7) * 4;
    const int sp  = tid >> 4;
    const int sn4 = (tid & 15) * 4;

    float rbA[4][4], rxA[4], rbB[4][4], rxB[4];   // named register sets
    float aA = 0.0f;
    f32x4 aoprev = {};
    int x0 = 0, x1 = 1, x2 = 2;

    // ---------------- prologue ----------------
    {
        const size_t iofs = (((size_t)bb*16 + hh)*64 + (ph*32 + sp))*(size_t)64 + sn4;
        const float4 v = *reinterpret_cast<const float4*>(&Ig[iofs]);
        sm.St32[sp][sn4+0] = v.x; sm.St32[sp][sn4+1] = v.y;
        sm.St32[sp][sn4+2] = v.z; sm.St32[sp][sn4+3] = v.w;
        *reinterpret_cast<bf16x4*>(&sm.St16[0][sp][sn4]) =
            (bf16x4){(__bf16)v.x, (__bf16)v.y, (__bf16)v.z, (__bf16)v.w};
    }
    #pragma unroll
    for (int j = 0; j < 4; ++j) {
        const int row = (half == 0) ? (lt0 + j) : (rr0 + 16*j);
        const size_t go = ((tbase + row)*16 + hh)*(size_t)64 + cq0;
        *reinterpret_cast<float4*>(rbA[j]) = (half == 0)
            ? *reinterpret_cast<const float4*>(&Bg[go])
            : *reinterpret_cast<const float4*>(&Cg[go]);
    }
    *reinterpret_cast<float4*>(rxA) =
        *reinterpret_cast<const float4*>(&Xg[((tbase + xl)*16 + hh)*(size_t)64 + ph*32 + xp4]);
    if (wid < 2) {   // scans for chunks 0,1
        float v = Ag[(tbase + wid*64 + lane)*16 + hh];
        #pragma unroll
        for (int o = 1; o < 64; o <<= 1) { float t = __shfl_up(v, o, 64); if (lane >= o) v += t; }
        const float last = __shfl(v, 63, 64);
        sm.ds[wid][lane]    = expf(last - v);
        sm.dout[wid][lane]  = expf(v);
        sm.douti[wid][lane] = expf(v - last);
        if (lane == 63) sm.dlast[wid] = expf(v);
    }
    if (half == 0) {
        #pragma unroll
        for (int j = 0; j < 4; ++j)
            *reinterpret_cast<bf16x4*>(&sm.Bm[0][lt0 + j][cq0]) =
                (bf16x4){(__bf16)rbA[j][0], (__bf16)rbA[j][1], (__bf16)rbA[j][2], (__bf16)rbA[j][3]};
        #pragma unroll
        for (int q = 0; q < 4; ++q)
            *reinterpret_cast<bf16x4*>(
                reinterpret_cast<char*>(&sm.Bt[0][cq0 + q][0]) + swz(cq0 + q, lt0*2)) =
                (bf16x4){(__bf16)rbA[0][q], (__bf16)rbA[1][q], (__bf16)rbA[2][q], (__bf16)rbA[3][q]};
    } else {
        #pragma unroll
        for (int j = 0; j < 4; ++j)
            *reinterpret_cast<bf16x4*>(&sm.Cm[0][rr0 + 16*j][cq0]) =
                (bf16x4){(__bf16)rbA[j][0], (__bf16)rbA[j][1], (__bf16)rbA[j][2], (__bf16)rbA[j][3]};
    }
    bar_lds();
    {
        const float dsl = sm.ds[0][xl];
        #pragma unroll
        for (int q = 0; q < 4; ++q)
            *reinterpret_cast<__bf16*>(
                reinterpret_cast<char*>(&sm.Xt[0][xp4 + q][0]) + swz(xp4 + q, xl*2)) =
                (__bf16)(rxA[q] * dsl);
    }
    #pragma unroll
    for (int j = 0; j < 4; ++j) {   // chunk-1 loads -> rbB
        const int row = (half == 0) ? (lt0 + j) : (rr0 + 16*j);
        const size_t go = ((tbase + 64 + row)*16 + hh)*(size_t)64 + cq0;
        *reinterpret_cast<float4*>(rbB[j]) = (half == 0)
            ? *reinterpret_cast<const float4*>(&Bg[go])
            : *reinterpret_cast<const float4*>(&Cg[go]);
    }
    *reinterpret_cast<float4*>(rxB) =
        *reinterpret_cast<const float4*>(&Xg[((tbase + 64 + xl)*16 + hh)*(size_t)64 + ph*32 + xp4]);
    if (wid == 0) aA = Ag[(tbase + 2*64 + lane)*16 + hh];
    bar_lds();

    // ---------------- chunk loop: unrolled x2, macro-expanded ----------------
    for (int cb = 0; cb < 64; cb += 2) {
        PHASE(cb,     0, rbA, rxA, rbB, rxB)   // even: prefetch->A, stage<-B
        PHASE(cb + 1, 1, rbB, rxB, rbA, rxA)   // odd:  prefetch->B, stage<-A
    }

    // ---------------- epilogue: ad(63), Y(62), Y(63) ----------------
    {
        f32x4 ad = {};
        #pragma unroll
        for (int ks = 0; ks < 2; ++ks) {
            const int k0 = ks*32 + fg*8;
            const bf16x8 aM = *reinterpret_cast<const bf16x8*>(&sm.Mm[1][iw2 + fr][k0]);
            const bf16x8 bX = *reinterpret_cast<const bf16x8*>(
                reinterpret_cast<const char*>(&sm.Xt[x2][pt + fr][0]) + swz(pt + fr, k0*2));
            ad = mfma16(aM, bX, ad);
        }
        #pragma unroll
        for (int r = 0; r < 4; ++r) {
            const int i = iw2 + fg*4 + r;
            sm.sY[0][i][pt + fr] = ad[r] + sm.dout[3][i] * aoprev[r];
        }
    }
    {
        const float4 v = *reinterpret_cast<const float4*>(&sm.sY[1][xl][xp4]);
        *reinterpret_cast<float4*>(
            &Yg[((tbase + (size_t)62*64 + xl)*16 + hh)*(size_t)64 + ph*32 + xp4]) = v;
    }
    bar_lds();
    {
        const float4 v = *reinterpret_cast<const float4*>(&sm.sY[0][xl][xp4]);
        *reinterpret_cast<float4*>(
            &Yg[((tbase + (size_t)63*64 + xl)*16 + hh)*(size_t)64 + ph*32 + xp4]) = v;
    }
}

extern "C" void kernel_launch(void* const* d_in, const int* in_sizes, int n_in,
                              void* d_out, int out_size, void* d_ws, size_t ws_size,
                              hipStream_t stream) {
    const float* X  = (const float*)d_in[0];
    const float* I  = (const float*)d_in[1];
    const float* A  = (const float*)d_in[2];
    const float* Bp = (const float*)d_in[3];
    const float* Cp = (const float*)d_in[4];
    float* Y = (float*)d_out;
    ssd_fused<<<dim3(2, 16, 8), 512, 0, stream>>>(X, I, A, Bp, Cp, Y);
}

// Round 18
// 140.399 us; speedup vs baseline: 2.2379x; 1.1579x over previous
//
#include <hip/hip_runtime.h>

// Mamba-2 SSD chunked scan — fused persistent kernel (round 18).
// Base = r13 EXACTLY (131.5us best: 1 barrier/chunk, buffered hazards,
// lgkm-only barrier, XOR swizzle, loads left to compiler scheduling — r17
// proved pinning them is a LOSS). Round-18 cuts shared-LDS-pipe work via
// mask structure (the real bottleneck: ~128 b128 reads + 64 scalar Mm writes
// per phase through one LDS pipe at 2 waves/SIMD):
//  (a) G lower-tri: 6/16 G tiles fully above diagonal -> skip mfma + B reads;
//      waves (iw2<32, jh=32) own only dead+unread tiles -> skip Mm writes.
//  (b) ad triangular-K: rows i<32 read only k<32 -> skip ad ks=1 for those
//      waves (loop AND epilogue — their Mm cols 32-63 are now unwritten).
//  (c) douti table -> dinv scalar (exp(cs_i-cs63) = dout[i]*exp(-cs63)).
// MFMA 80->64, b128 reads 128->~108, Mm writes -25% per chunk.
// Canaries: WRITE_SIZE==131072 KB, VGPR~64, absmax<=1.

typedef __bf16 bf16x4 __attribute__((ext_vector_type(4)));
typedef __bf16 bf16x8 __attribute__((ext_vector_type(8)));
typedef float  f32x4  __attribute__((ext_vector_type(4)));

constexpr int LDT = 72;   // bf16 row stride (144 B)

__device__ __forceinline__ f32x4 mfma16(bf16x8 a, bf16x8 b, f32x4 c) {
    return __builtin_amdgcn_mfma_f32_16x16x32_bf16(a, b, c, 0, 0, 0);
}
// LDS-only barrier: does NOT drain vmcnt (global reg-prefetches stay in flight)
__device__ __forceinline__ void bar_lds() {
    asm volatile("s_waitcnt lgkmcnt(0)\n\ts_barrier" ::: "memory");
}
// XOR swizzle for transposed buffers (16B granularity, rows grouped by 4)
__device__ __forceinline__ int swz(int row, int byteoff) {
    return byteoff ^ (((row >> 2) & 7) << 4);
}

struct SMemF {
    __bf16 Cm[2][64][LDT];   // C row-major [l][n]
    __bf16 Bm[2][64][LDT];   // B row-major [l][n]
    __bf16 Bt[2][64][LDT];   // B^T [n][l] (swizzled)
    __bf16 Mm[2][64][LDT];   // M' [i][j]
    __bf16 Xt[3][32][LDT];   // Xs^T [p][l] (swizzled, TRIPLE)
    __bf16 St16[2][32][LDT]; // state bf16 operand copy (parity)
    float  St32[32][68];     // state f32 master (per-lane exclusive)
    float  sY[2][64][36];    // Y staging (parity)
    float  ds[4][64];        // e^{cs63-cs_l}   } quad-buffered (c%4)
    float  dout[4][64];      // e^{cs_i}
    float  dlast[4];         // e^{cs63}
    float  dinv[4];          // e^{-cs63}
};

__global__ void ssd_fused(const float* __restrict__ Xg, const float* __restrict__ Ig,
                          const float* __restrict__ Ag, const float* __restrict__ Bg,
                          const float* __restrict__ Cg, float* __restrict__ Yg)
{
    const int ph = blockIdx.x, hh = blockIdx.y, bb = blockIdx.z;
    const int tid = threadIdx.x;            // 0..511
    const int wid = tid >> 6, lane = tid & 63;
    const int fr = lane & 15, fg = lane >> 4;
    const int iw2 = (wid >> 1) * 16;        // i-strip / n-strip
    const int pt  = (wid & 1) * 16;         // p-tile
    const int jh  = (wid & 1) * 32;         // G j-half base

    // mask-structure flags (wave-uniform)
    const bool dG0 = (jh      > iw2 + 15);  // g0 tile fully above diagonal
    const bool dG1 = (jh + 16 > iw2 + 15);  // g1 tile fully above diagonal
    const bool skipMm = dG0 && dG1;         // waves (0,32),(16,32): region never read
    const bool adFull = (iw2 >= 32);        // ad needs ks=1 only for i>=32

    __shared__ __align__(16) SMemF sm;
    const size_t tbase = (size_t)bb * 4096;

    const int half = tid >> 8;              // 0: B rows (+transpose), 1: C rows
    const int u    = tid & 255;
    const int lt0  = (u >> 4) * 4;
    const int rr0  = u >> 4;
    const int cq0  = (u & 15) * 4;
    const int xl  = tid >> 3;               // X/Y row 0..63
    const int xp4 = (tid & 7) * 4;          // X/Y p quad
    const int sp  = tid >> 4;               // St row 0..31
    const int sn4 = (tid & 15) * 4;

    float rb[4][4], rx[4];
    float aA = 0.0f;

    auto scan_to = [&](float v, int tb) {
        #pragma unroll
        for (int o = 1; o < 64; o <<= 1) { float t = __shfl_up(v, o, 64); if (lane >= o) v += t; }
        const float last = __shfl(v, 63, 64);
        sm.ds[tb][lane]   = expf(last - v);
        sm.dout[tb][lane] = expf(v);
        if (lane == 63) { sm.dlast[tb] = expf(v); sm.dinv[tb] = expf(-v); }
    };

    // ---------------- prologue ----------------
    {   // initial state -> St32 + St16[0]
        const size_t iofs = (((size_t)bb*16 + hh)*64 + (ph*32 + sp))*(size_t)64 + sn4;
        const float4 v = *reinterpret_cast<const float4*>(&Ig[iofs]);
        sm.St32[sp][sn4+0] = v.x; sm.St32[sp][sn4+1] = v.y;
        sm.St32[sp][sn4+2] = v.z; sm.St32[sp][sn4+3] = v.w;
        *reinterpret_cast<bf16x4*>(&sm.St16[0][sp][sn4]) =
            (bf16x4){(__bf16)v.x, (__bf16)v.y, (__bf16)v.z, (__bf16)v.w};
    }
    // chunk-0 loads
    #pragma unroll
    for (int j = 0; j < 4; ++j) {
        const int row = (half == 0) ? (lt0 + j) : (rr0 + 16*j);
        const size_t go = ((tbase + row)*16 + hh)*(size_t)64 + cq0;
        *reinterpret_cast<float4*>(rb[j]) = (half == 0)
            ? *reinterpret_cast<const float4*>(&Bg[go])
            : *reinterpret_cast<const float4*>(&Cg[go]);
    }
    *reinterpret_cast<float4*>(rx) =
        *reinterpret_cast<const float4*>(&Xg[((tbase + xl)*16 + hh)*(size_t)64 + ph*32 + xp4]);
    // scans for chunks 0,1 (waves 0,1 in parallel)
    if (wid < 2) {
        const float v = Ag[(tbase + wid*64 + lane)*16 + hh];
        scan_to(v, wid);
    }
    // stage chunk-0 C/B/Bt into parity-0 buffers
    if (half == 0) {
        #pragma unroll
        for (int j = 0; j < 4; ++j)
            *reinterpret_cast<bf16x4*>(&sm.Bm[0][lt0 + j][cq0]) =
                (bf16x4){(__bf16)rb[j][0], (__bf16)rb[j][1], (__bf16)rb[j][2], (__bf16)rb[j][3]};
        #pragma unroll
        for (int q = 0; q < 4; ++q)
            *reinterpret_cast<bf16x4*>(
                reinterpret_cast<char*>(&sm.Bt[0][cq0 + q][0]) + swz(cq0 + q, lt0*2)) =
                (bf16x4){(__bf16)rb[0][q], (__bf16)rb[1][q], (__bf16)rb[2][q], (__bf16)rb[3][q]};
    } else {
        #pragma unroll
        for (int j = 0; j < 4; ++j)
            *reinterpret_cast<bf16x4*>(&sm.Cm[0][rr0 + 16*j][cq0]) =
                (bf16x4){(__bf16)rb[j][0], (__bf16)rb[j][1], (__bf16)rb[j][2], (__bf16)rb[j][3]};
    }
    bar_lds();   // tables[0],[1] + St + chunk-0 stage visible
    {   // stage Xt[0] (needs ds[0])
        const float dsl = sm.ds[0][xl];
        #pragma unroll
        for (int q = 0; q < 4; ++q)
            *reinterpret_cast<__bf16*>(
                reinterpret_cast<char*>(&sm.Xt[0][xp4 + q][0]) + swz(xp4 + q, xl*2)) =
                (__bf16)(rx[q] * dsl);
    }
    // chunk-1 loads (rb consumed above); wave0 preloads A(2)
    #pragma unroll
    for (int j = 0; j < 4; ++j) {
        const int row = (half == 0) ? (lt0 + j) : (rr0 + 16*j);
        const size_t go = ((tbase + 64 + row)*16 + hh)*(size_t)64 + cq0;
        *reinterpret_cast<float4*>(rb[j]) = (half == 0)
            ? *reinterpret_cast<const float4*>(&Bg[go])
            : *reinterpret_cast<const float4*>(&Cg[go]);
    }
    *reinterpret_cast<float4*>(rx) =
        *reinterpret_cast<const float4*>(&Xg[((tbase + 64 + xl)*16 + hh)*(size_t)64 + ph*32 + xp4]);
    if (wid == 0) aA = Ag[(tbase + 2*64 + lane)*16 + hh];
    bar_lds();   // Xt[0] visible

    f32x4 aoprev = {};
    int x0 = 0, x1 = 1, x2 = 2;   // Xt buffers: c%3, (c+1)%3, (c-1)%3

    // ---------------- chunk loop: ONE barrier per chunk ----------------
    for (int c = 0; c < 64; ++c) {
        const int ci = c & 1, nb = ci ^ 1;
        const int t0 = c & 3, t1 = (c+1) & 3, t2 = (c+2) & 3, t3 = (c+3) & 3;

        // ---- MFMA cluster: chunk c (g/ao/st), dead G tiles skipped ----
        f32x4 g0 = {}, g1 = {}, aoacc = {}, stacc = {};
        #pragma unroll
        for (int ks = 0; ks < 2; ++ks) {
            const int k0 = ks*32 + fg*8;
            const bf16x8 aC  = *reinterpret_cast<const bf16x8*>(&sm.Cm[ci][iw2 + fr][k0]);
            const bf16x8 bSt = *reinterpret_cast<const bf16x8*>(&sm.St16[ci][pt + fr][k0]);
            const bf16x8 aBt = *reinterpret_cast<const bf16x8*>(
                reinterpret_cast<const char*>(&sm.Bt[ci][iw2 + fr][0]) + swz(iw2 + fr, k0*2));
            const bf16x8 bXt = *reinterpret_cast<const bf16x8*>(
                reinterpret_cast<const char*>(&sm.Xt[x0][pt + fr][0]) + swz(pt + fr, k0*2));
            aoacc = mfma16(aC,  bSt, aoacc);
            stacc = mfma16(aBt, bXt, stacc);
            if (!dG0) {
                const bf16x8 bB0 = *reinterpret_cast<const bf16x8*>(&sm.Bm[ci][jh + fr][k0]);
                g0 = mfma16(aC, bB0, g0);
            }
            if (!dG1) {
                const bf16x8 bB1 = *reinterpret_cast<const bf16x8*>(&sm.Bm[ci][jh + 16 + fr][k0]);
                g1 = mfma16(aC, bB1, g1);
            }
        }
        // ---- ad(c-1) = M'(c-1) @ Xs(c-1), triangular K (ks=1 only if i>=32) ----
        f32x4 ad = {};
        if (c > 0) {
            {
                const int k0 = fg*8;
                const bf16x8 aM = *reinterpret_cast<const bf16x8*>(&sm.Mm[nb][iw2 + fr][k0]);
                const bf16x8 bX = *reinterpret_cast<const bf16x8*>(
                    reinterpret_cast<const char*>(&sm.Xt[x2][pt + fr][0]) + swz(pt + fr, k0*2));
                ad = mfma16(aM, bX, ad);
            }
            if (adFull) {
                const int k0 = 32 + fg*8;
                const bf16x8 aM = *reinterpret_cast<const bf16x8*>(&sm.Mm[nb][iw2 + fr][k0]);
                const bf16x8 bX = *reinterpret_cast<const bf16x8*>(
                    reinterpret_cast<const char*>(&sm.Xt[x2][pt + fr][0]) + swz(pt + fr, k0*2));
                ad = mfma16(aM, bX, ad);
            }
        }
        // ---- scan(c+2) -> tables[t2] ----
        if (c <= 61 && wid == 0) scan_to(aA, t2);
        // ---- Y store(c-2) from sY[nb] ----
        if (c >= 2) {
            const float4 v = *reinterpret_cast<const float4*>(&sm.sY[nb][xl][xp4]);
            *reinterpret_cast<float4*>(
                &Yg[((tbase + (size_t)(c-2)*64 + xl)*16 + hh)*(size_t)64 + ph*32 + xp4]) = v;
        }
        // ---- stage(c+1) into parity-nb / Xt[x1] ----
        if (c < 63) {
            if (half == 0) {
                #pragma unroll
                for (int j = 0; j < 4; ++j)
                    *reinterpret_cast<bf16x4*>(&sm.Bm[nb][lt0 + j][cq0]) =
                        (bf16x4){(__bf16)rb[j][0], (__bf16)rb[j][1], (__bf16)rb[j][2], (__bf16)rb[j][3]};
                #pragma unroll
                for (int q = 0; q < 4; ++q)
                    *reinterpret_cast<bf16x4*>(
                        reinterpret_cast<char*>(&sm.Bt[nb][cq0 + q][0]) + swz(cq0 + q, lt0*2)) =
                        (bf16x4){(__bf16)rb[0][q], (__bf16)rb[1][q], (__bf16)rb[2][q], (__bf16)rb[3][q]};
            } else {
                #pragma unroll
                for (int j = 0; j < 4; ++j)
                    *reinterpret_cast<bf16x4*>(&sm.Cm[nb][rr0 + 16*j][cq0]) =
                        (bf16x4){(__bf16)rb[j][0], (__bf16)rb[j][1], (__bf16)rb[j][2], (__bf16)rb[j][3]};
            }
            const float dsl = sm.ds[t1][xl];
            #pragma unroll
            for (int q = 0; q < 4; ++q)
                *reinterpret_cast<__bf16*>(
                    reinterpret_cast<char*>(&sm.Xt[x1][xp4 + q][0]) + swz(xp4 + q, xl*2)) =
                    (__bf16)(rx[q] * dsl);
        }
        // ---- prefetch chunk c+2 (rb consumed by stage above) ----
        if (c < 62) {
            const size_t s2 = tbase + (size_t)(c + 2)*64;
            #pragma unroll
            for (int j = 0; j < 4; ++j) {
                const int row = (half == 0) ? (lt0 + j) : (rr0 + 16*j);
                const size_t go = ((s2 + row)*16 + hh)*(size_t)64 + cq0;
                *reinterpret_cast<float4*>(rb[j]) = (half == 0)
                    ? *reinterpret_cast<const float4*>(&Bg[go])
                    : *reinterpret_cast<const float4*>(&Cg[go]);
            }
            *reinterpret_cast<float4*>(rx) =
                *reinterpret_cast<const float4*>(&Xg[((s2 + xl)*16 + hh)*(size_t)64 + ph*32 + xp4]);
        }
        if (wid == 0 && c <= 60) aA = Ag[(tbase + (size_t)(c + 3)*64 + lane)*16 + hh];
        // ---- sY[ci] write = Y(c-1) ----
        if (c > 0) {
            #pragma unroll
            for (int r = 0; r < 4; ++r) {
                const int i = iw2 + fg*4 + r;
                sm.sY[ci][i][pt + fr] = ad[r] + sm.dout[t3][i] * aoprev[r];
            }
        }
        // ---- Mm[ci] write = mask(G)*dout[i]*e^{-cs63} (skipped if unread) ----
        if (!skipMm) {
            const float dinvv = sm.dinv[t0];
            #pragma unroll
            for (int jt = 0; jt < 2; ++jt) {
                const int j = jh + jt*16 + fr;
                const f32x4& gg = jt ? g1 : g0;
                #pragma unroll
                for (int r = 0; r < 4; ++r) {
                    const int i = iw2 + fg*4 + r;
                    const float val = (i >= j) ? gg[r] * sm.dout[t0][i] * dinvv : 0.0f;
                    sm.Mm[ci][i][j] = (__bf16)val;
                }
            }
        }
        // ---- St update -> St32 + St16[nb] ----
        if (c < 63) {
            const float dl = sm.dlast[t0];
            const int p = pt + fr, n0 = iw2 + fg*4;
            const float4 ov = *reinterpret_cast<const float4*>(&sm.St32[p][n0]);
            float4 nv;
            nv.x = fmaf(dl, ov.x, stacc[0]); nv.y = fmaf(dl, ov.y, stacc[1]);
            nv.z = fmaf(dl, ov.z, stacc[2]); nv.w = fmaf(dl, ov.w, stacc[3]);
            *reinterpret_cast<float4*>(&sm.St32[p][n0]) = nv;
            *reinterpret_cast<bf16x4*>(&sm.St16[nb][p][n0]) =
                (bf16x4){(__bf16)nv.x, (__bf16)nv.y, (__bf16)nv.z, (__bf16)nv.w};
        }
        aoprev = aoacc;
        bar_lds();   // the ONE barrier
        const int xt = x0; x0 = x1; x1 = x2; x2 = xt;   // rotate Xt buffers
    }

    // ---------------- epilogue: ad(63), Y(62), Y(63) ----------------
    {
        f32x4 ad = {};
        {
            const int k0 = fg*8;
            const bf16x8 aM = *reinterpret_cast<const bf16x8*>(&sm.Mm[1][iw2 + fr][k0]);
            const bf16x8 bX = *reinterpret_cast<const bf16x8*>(
                reinterpret_cast<const char*>(&sm.Xt[x2][pt + fr][0]) + swz(pt + fr, k0*2));
            ad = mfma16(aM, bX, ad);
        }
        if (adFull) {
            const int k0 = 32 + fg*8;
            const bf16x8 aM = *reinterpret_cast<const bf16x8*>(&sm.Mm[1][iw2 + fr][k0]);
            const bf16x8 bX = *reinterpret_cast<const bf16x8*>(
                reinterpret_cast<const char*>(&sm.Xt[x2][pt + fr][0]) + swz(pt + fr, k0*2));
            ad = mfma16(aM, bX, ad);
        }
        #pragma unroll
        for (int r = 0; r < 4; ++r) {
            const int i = iw2 + fg*4 + r;
            sm.sY[0][i][pt + fr] = ad[r] + sm.dout[3][i] * aoprev[r];
        }
    }
    {   // Y(62) from sY[1] (written in phase 63; loop-end barrier synced)
        const float4 v = *reinterpret_cast<const float4*>(&sm.sY[1][xl][xp4]);
        *reinterpret_cast<float4*>(
            &Yg[((tbase + (size_t)62*64 + xl)*16 + hh)*(size_t)64 + ph*32 + xp4]) = v;
    }
    bar_lds();
    {   // Y(63) from sY[0]
        const float4 v = *reinterpret_cast<const float4*>(&sm.sY[0][xl][xp4]);
        *reinterpret_cast<float4*>(
            &Yg[((tbase + (size_t)63*64 + xl)*16 + hh)*(size_t)64 + ph*32 + xp4]) = v;
    }
}

extern "C" void kernel_launch(void* const* d_in, const int* in_sizes, int n_in,
                              void* d_out, int out_size, void* d_ws, size_t ws_size,
                              hipStream_t stream) {
    const float* X  = (const float*)d_in[0];
    const float* I  = (const float*)d_in[1];
    const float* A  = (const float*)d_in[2];
    const float* Bp = (const float*)d_in[3];
    const float* Cp = (const float*)d_in[4];
    float* Y = (float*)d_out;
    ssd_fused<<<dim3(2, 16, 8), 512, 0, stream>>>(X, I, A, Bp, Cp, Y);
}